// Round 1
// baseline (154.496 us; speedup 1.0000x reference)
//
#include <hip/hip_runtime.h>
#include <stdint.h>

#define BB 4
#define LL 2048
#define DD 256
#define SLOTS 64
#define NG 3
#define MN 192            // SLOTS*NG
#define P_TOTAL (BB*LL)   // 8192
#define TL 16             // l-positions per gather block

// K1: S[p][mn] = dot(x[p,:], memory[mn,:]) + bias[mn]
// grid 256 blocks x 192 threads; each block handles 32 p-rows, thread = one mn row.
__global__ __launch_bounds__(192) void score_kernel(
    const float* __restrict__ x, const float* __restrict__ mem,
    const float* __restrict__ bias, float* __restrict__ S)
{
    __shared__ float xs[32 * DD];   // 32 KB
    const int p0 = blockIdx.x * 32;

    // stage 32 x-rows into LDS (coalesced float4)
    const float4* xg  = (const float4*)(x + (size_t)p0 * DD);
    float4*       xs4 = (float4*)xs;
    for (int idx = threadIdx.x; idx < 32 * (DD / 4); idx += 192) {
        xs4[idx] = xg[idx];
    }
    __syncthreads();

    const int mn = threadIdx.x;     // 0..191
    float acc[32];
#pragma unroll
    for (int r = 0; r < 32; ++r) acc[r] = 0.f;

    const float4* mrow = (const float4*)(mem + mn * DD);

#pragma unroll 1
    for (int kc = 0; kc < DD / 4; kc += 8) {   // 8 chunks of 32 floats
        float4 m4[8];
#pragma unroll
        for (int j = 0; j < 8; ++j) m4[j] = mrow[kc + j];
#pragma unroll
        for (int r = 0; r < 32; ++r) {
            const float4* xr = xs4 + r * (DD / 4) + kc;  // broadcast LDS reads
            float s = 0.f;
#pragma unroll
            for (int j = 0; j < 8; ++j) {
                const float4 xv = xr[j];
                s += xv.x * m4[j].x;
                s += xv.y * m4[j].y;
                s += xv.z * m4[j].z;
                s += xv.w * m4[j].w;
            }
            acc[r] += s;
        }
    }

    const float bmn = bias[mn];
#pragma unroll
    for (int r = 0; r < 32; ++r) {
        S[(size_t)(p0 + r) * MN + mn] = acc[r] + bmn;   // mn-coalesced store
    }
}

// K2: argmax over n (first-max tiebreak) + gather-sum of memory rows.
// grid 512 blocks x 256 threads; each block handles TL=16 p-rows.
__global__ __launch_bounds__(256) void gather_kernel(
    const float* __restrict__ S, const float* __restrict__ mem,
    const float* __restrict__ bias, float* __restrict__ out)
{
    __shared__ unsigned char bestS[TL][SLOTS];
    __shared__ float biasS[MN];

    const int p0 = blockIdx.x * TL;

    if (threadIdx.x < MN) biasS[threadIdx.x] = bias[threadIdx.x];
    __syncthreads();

    // phase 1: argmax for TL*64 = 1024 (li, m) tasks
    for (int t = threadIdx.x; t < TL * SLOTS; t += 256) {
        const int li = t >> 6;
        const int m  = t & 63;
        const int p  = p0 + li;
        const int l  = p & (LL - 1);   // position within batch row
        // n-th ngram at l uses x row (l-2+n); zero ngram => score == bias
        const float v0 = (l >= 2) ? S[(size_t)(p - 2) * MN + m * 3 + 0] : biasS[m * 3 + 0];
        const float v1 = (l >= 1) ? S[(size_t)(p - 1) * MN + m * 3 + 1] : biasS[m * 3 + 1];
        const float v2 =            S[(size_t)(p    ) * MN + m * 3 + 2];
        int bn = 0; float bv = v0;
        if (v1 > bv) { bv = v1; bn = 1; }   // strict > : first max wins (np.argmax)
        if (v2 > bv) { bv = v2; bn = 2; }
        bestS[li][m] = (unsigned char)bn;
    }
    __syncthreads();

    // phase 2: out[p][:] = sum_m mem[m*3 + best][:], float4 per thread
    const int li0 = threadIdx.x >> 6;   // 0..3 (wave-uniform)
    const int d4  = threadIdx.x & 63;   // float4 lane
    const float4* mem4 = (const float4*)mem;
    float4* out4 = (float4*)out;

    for (int lb = 0; lb < TL; lb += 4) {
        const int li = lb + li0;
        float4 a = make_float4(0.f, 0.f, 0.f, 0.f);
#pragma unroll
        for (int m = 0; m < SLOTS; ++m) {
            const int n = bestS[li][m];                        // wave-uniform
            const float4 v = mem4[(m * 3 + n) * (DD / 4) + d4]; // 1KB coalesced, L2-hit
            a.x += v.x; a.y += v.y; a.z += v.z; a.w += v.w;
        }
        out4[(size_t)(p0 + li) * (DD / 4) + d4] = a;
    }
}

extern "C" void kernel_launch(void* const* d_in, const int* in_sizes, int n_in,
                              void* d_out, int out_size, void* d_ws, size_t ws_size,
                              hipStream_t stream) {
    const float* x    = (const float*)d_in[0];   // (B, L, D)
    const float* mem  = (const float*)d_in[1];   // (SLOTS, NG, D)
    const float* bias = (const float*)d_in[2];   // (SLOTS, NG)
    float* out = (float*)d_out;                  // (B, L, D)
    float* S   = (float*)d_ws;                   // (P_TOTAL, MN) = 6.29 MB

    score_kernel<<<P_TOTAL / 32, 192, 0, stream>>>(x, mem, bias, S);
    gather_kernel<<<P_TOTAL / TL, 256, 0, stream>>>(S, mem, bias, out);
}

// Round 2
// 125.025 us; speedup vs baseline: 1.2357x; 1.2357x over previous
//
#include <hip/hip_runtime.h>
#include <stdint.h>

#define BB 4
#define LL 2048
#define DD 256
#define SLOTS 64
#define NG 3
#define MN 192            // SLOTS*NG
#define P_TOTAL (BB*LL)   // 8192
#define PB 16             // p rows per score block
#define GP 32             // p rows per gather block

// K1: S[p][mn] = dot(x[p,:], memory[mn,:]) + bias[mn]
// grid 512 x 384 threads. Thread (c = tid%96, pg = tid/96) computes
// mn in {c, c+96} for p in {p0+pg*4 .. +3}: one LDS x-read feeds 8 FMAs.
__global__ __launch_bounds__(384) void score_kernel(
    const float* __restrict__ x, const float* __restrict__ mem,
    const float* __restrict__ bias, float* __restrict__ S)
{
    __shared__ float xs[PB * DD];   // 16 KB
    const int p0 = blockIdx.x * PB;

    const float4* xg  = (const float4*)(x + (size_t)p0 * DD);
    float4*       xs4 = (float4*)xs;
    for (int i = threadIdx.x; i < PB * (DD / 4); i += 384) xs4[i] = xg[i];
    __syncthreads();

    const int c  = threadIdx.x % 96;
    const int pg = threadIdx.x / 96;   // 0..3

    const float4* m0 = (const float4*)(mem + (size_t)c * DD);
    const float4* m1 = (const float4*)(mem + (size_t)(c + 96) * DD);
    const float4* xr = xs4 + pg * 4 * (DD / 4);

    float acc[4][2];
#pragma unroll
    for (int r = 0; r < 4; ++r) { acc[r][0] = 0.f; acc[r][1] = 0.f; }

#pragma unroll 4
    for (int j = 0; j < DD / 4; ++j) {
        const float4 a0 = m0[j];
        const float4 a1 = m1[j];
#pragma unroll
        for (int r = 0; r < 4; ++r) {
            const float4 xv = xr[r * (DD / 4) + j];
            acc[r][0] += xv.x * a0.x + xv.y * a0.y + xv.z * a0.z + xv.w * a0.w;
            acc[r][1] += xv.x * a1.x + xv.y * a1.y + xv.z * a1.z + xv.w * a1.w;
        }
    }

    const float b0 = bias[c];
    const float b1 = bias[c + 96];
#pragma unroll
    for (int r = 0; r < 4; ++r) {
        const int p = p0 + pg * 4 + r;
        S[(size_t)p * MN + c]      = acc[r][0] + b0;
        S[(size_t)p * MN + c + 96] = acc[r][1] + b1;
    }
}

// K2: argmax over n + gather-sum, with memory staged in LDS as bf16.
// grid 256 x 1024 threads (16 waves, 1 block/CU). Block handles 32 p-rows.
__global__ __launch_bounds__(1024) void gather_kernel(
    const float* __restrict__ S, const float* __restrict__ mem,
    const float* __restrict__ bias, float* __restrict__ out)
{
    __shared__ unsigned int  ms[MN * (DD / 2)];  // bf16-packed memory, 96 KB
    __shared__ unsigned char bestS[GP][SLOTS];   // 2 KB
    __shared__ float         biasS[MN];

    const int p0 = blockIdx.x * GP;

    if (threadIdx.x < MN) biasS[threadIdx.x] = bias[threadIdx.x];

    // stage memory -> bf16 (round half up) packed 2/uint
    const float4* mem4 = (const float4*)mem;
    for (int i = threadIdx.x; i < MN * (DD / 4); i += 1024) {
        const float4 v = mem4[i];
        const unsigned int bx = __float_as_uint(v.x), by = __float_as_uint(v.y);
        const unsigned int bz = __float_as_uint(v.z), bw = __float_as_uint(v.w);
        const unsigned int u0 = ((bx + 0x8000u) >> 16) | ((by + 0x8000u) & 0xffff0000u);
        const unsigned int u1 = ((bz + 0x8000u) >> 16) | ((bw + 0x8000u) & 0xffff0000u);
        ms[2 * i]     = u0;
        ms[2 * i + 1] = u1;
    }
    __syncthreads();

    // phase 1: argmax for GP*64 = 2048 (li, m) tasks (first-max tiebreak)
    for (int t = threadIdx.x; t < GP * SLOTS; t += 1024) {
        const int li = t >> 6;
        const int m  = t & 63;
        const int p  = p0 + li;
        const int l  = p & (LL - 1);
        const float v0 = (l >= 2) ? S[(size_t)(p - 2) * MN + m * 3 + 0] : biasS[m * 3 + 0];
        const float v1 = (l >= 1) ? S[(size_t)(p - 1) * MN + m * 3 + 1] : biasS[m * 3 + 1];
        const float v2 =            S[(size_t)(p    ) * MN + m * 3 + 2];
        int bn = 0; float bv = v0;
        if (v1 > bv) { bv = v1; bn = 1; }
        if (v2 > bv) { bv = v2; bn = 2; }
        bestS[li][m] = (unsigned char)bn;
    }
    __syncthreads();

    // phase 2: out[p][:] = sum_m mem[m*3+best][:] from LDS bf16.
    // wave w handles p-rows 2w, 2w+1; lane = float4 column.
    const int wave = threadIdx.x >> 6;
    const int lane = threadIdx.x & 63;
    const uint2* ms2 = (const uint2*)ms;
    float4* out4 = (float4*)out;

#pragma unroll
    for (int r = 0; r < 2; ++r) {
        const int li = wave * 2 + r;
        float4 a = make_float4(0.f, 0.f, 0.f, 0.f);
#pragma unroll 4
        for (int m = 0; m < SLOTS; ++m) {
            const int n = bestS[li][m];
            const uint2 q = ms2[(m * 3 + n) * (DD / 4) + lane];
            a.x += __uint_as_float(q.x << 16);
            a.y += __uint_as_float(q.x & 0xffff0000u);
            a.z += __uint_as_float(q.y << 16);
            a.w += __uint_as_float(q.y & 0xffff0000u);
        }
        out4[(size_t)(p0 + li) * (DD / 4) + lane] = a;
    }
}

extern "C" void kernel_launch(void* const* d_in, const int* in_sizes, int n_in,
                              void* d_out, int out_size, void* d_ws, size_t ws_size,
                              hipStream_t stream) {
    const float* x    = (const float*)d_in[0];   // (B, L, D)
    const float* mem  = (const float*)d_in[1];   // (SLOTS, NG, D)
    const float* bias = (const float*)d_in[2];   // (SLOTS, NG)
    float* out = (float*)d_out;                  // (B, L, D)
    float* S   = (float*)d_ws;                   // (P_TOTAL, MN) = 6.29 MB

    score_kernel<<<P_TOTAL / PB, 384, 0, stream>>>(x, mem, bias, S);
    gather_kernel<<<P_TOTAL / GP, 1024, 0, stream>>>(S, mem, bias, out);
}

// Round 3
// 124.539 us; speedup vs baseline: 1.2405x; 1.0039x over previous
//
#include <hip/hip_runtime.h>
#include <stdint.h>

#define LL 2048
#define DD 256
#define SLOTS 64
#define NG 3
#define MN 192
#define PT 8192            // total p rows (B*L)

// ---------------- K1: score GEMM ----------------
// S[mn][p] = dot(x[p,:], mem[mn,:]) + bias[mn]   (S layout transposed: mn-major)
// grid 256 = 128 p-tiles x 2 mn-halves; block 512 thr = 8 waves.
// wave w: lane = p (64 rows), 12 mn rows each; m values via uniform s_load,
// x from LDS (stride-65-float4 padding, conflict-free b128).
__global__ __launch_bounds__(512) void score_kernel(
    const float* __restrict__ x, const float* __restrict__ mem,
    const float* __restrict__ bias, float* __restrict__ S)
{
    __shared__ float xs[64 * 260];  // 64 rows padded to 260 floats = 66.56 KB

    const int pt = blockIdx.x & 127;
    const int ms = blockIdx.x >> 7;        // 0 or 1 (mn half)
    const int p0 = pt * 64;

    // stage x tile (coalesced float4)
    const float4* xg  = (const float4*)(x + (size_t)p0 * DD);
    float4*       xs4 = (float4*)xs;
    for (int i = threadIdx.x; i < 64 * 64; i += 512) {
        const int r = i >> 6, j = i & 63;
        xs4[r * 65 + j] = xg[i];
    }
    __syncthreads();

    const int lane = threadIdx.x & 63;
    const int w    = __builtin_amdgcn_readfirstlane(threadIdx.x >> 6);
    const int mn_base = ms * 96 + w * 12;   // wave-uniform

    // 12 uniform row pointers -> scalar loads
    const float* mr0  = mem + (size_t)(mn_base + 0)  * DD;
    const float* mr1  = mem + (size_t)(mn_base + 1)  * DD;
    const float* mr2  = mem + (size_t)(mn_base + 2)  * DD;
    const float* mr3  = mem + (size_t)(mn_base + 3)  * DD;
    const float* mr4  = mem + (size_t)(mn_base + 4)  * DD;
    const float* mr5  = mem + (size_t)(mn_base + 5)  * DD;
    const float* mr6  = mem + (size_t)(mn_base + 6)  * DD;
    const float* mr7  = mem + (size_t)(mn_base + 7)  * DD;
    const float* mr8  = mem + (size_t)(mn_base + 8)  * DD;
    const float* mr9  = mem + (size_t)(mn_base + 9)  * DD;
    const float* mr10 = mem + (size_t)(mn_base + 10) * DD;
    const float* mr11 = mem + (size_t)(mn_base + 11) * DD;
    const float* mrows[12] = {mr0,mr1,mr2,mr3,mr4,mr5,mr6,mr7,mr8,mr9,mr10,mr11};

    float acc[12];
#pragma unroll
    for (int i = 0; i < 12; ++i) acc[i] = 0.f;

    const float4* xlane = (const float4*)(xs + lane * 260);

#pragma unroll 2
    for (int c = 0; c < 16; ++c) {          // k-chunks of 16 floats
        float4 xv[4];
#pragma unroll
        for (int t = 0; t < 4; ++t) xv[t] = xlane[c * 4 + t];
        const float* xf = (const float*)xv;
#pragma unroll
        for (int i = 0; i < 12; ++i) {
            const float* m = mrows[i] + c * 16;   // uniform addr -> s_load
            float s = 0.f;
#pragma unroll
            for (int k = 0; k < 16; ++k) s += xf[k] * m[k];
            acc[i] += s;
        }
    }

    const int p = p0 + lane;
#pragma unroll
    for (int i = 0; i < 12; ++i) {
        S[(size_t)(mn_base + i) * PT + p] = acc[i] + bias[mn_base + i];
    }
}

// ---------------- K2: argmax + gather-sum ----------------
// grid 256 x 512 thr (8 waves); block handles 32 p rows; memory in LDS as bf16.
__global__ __launch_bounds__(512) void gather_kernel(
    const float* __restrict__ S, const float* __restrict__ mem,
    const float* __restrict__ bias, float* __restrict__ out)
{
    __shared__ uint32_t      msd[MN * (DD / 2)];   // bf16-packed memory, 96 KB
    __shared__ float         biasS[MN];
    __shared__ unsigned char bestS[32][64];        // 2 KB

    const int p0 = blockIdx.x * 32;

    // stage memory -> bf16 (round half up), packed 2/uint
    const float4* mem4 = (const float4*)mem;
    for (int i = threadIdx.x; i < MN * (DD / 4); i += 512) {
        const float4 v = mem4[i];
        const uint32_t bx = __float_as_uint(v.x), by = __float_as_uint(v.y);
        const uint32_t bz = __float_as_uint(v.z), bw = __float_as_uint(v.w);
        msd[2 * i]     = ((bx + 0x8000u) >> 16) | ((by + 0x8000u) & 0xffff0000u);
        msd[2 * i + 1] = ((bz + 0x8000u) >> 16) | ((bw + 0x8000u) & 0xffff0000u);
    }
    if (threadIdx.x < MN) biasS[threadIdx.x] = bias[threadIdx.x];
    __syncthreads();

    // phase 1: argmax (first-max tiebreak) for 32p x 64m tasks.
    // S reads coalesced in p (lane-low = p).
    for (int t = threadIdx.x; t < 32 * SLOTS; t += 512) {
        const int m = t >> 5;
        const int s = t & 31;
        const int p = p0 + s;
        const int l = p & (LL - 1);
        const float v0 = (l >= 2) ? S[(size_t)(3 * m + 0) * PT + p - 2] : biasS[3 * m + 0];
        const float v1 = (l >= 1) ? S[(size_t)(3 * m + 1) * PT + p - 1] : biasS[3 * m + 1];
        const float v2 =            S[(size_t)(3 * m + 2) * PT + p];
        int bn = 0; float bv = v0;
        if (v1 > bv) { bv = v1; bn = 1; }
        if (v2 > bv) { bv = v2; bn = 2; }
        bestS[s][m] = (unsigned char)bn;
    }
    __syncthreads();

    // phase 2: out[p][:] = sum_m mem[m*3+best][:]
    // wave w handles 4 p rows; half-waves process even/odd m simultaneously:
    // one ds_read_b128 covers two full bf16 rows (1 KB).
    const int lane = threadIdx.x & 63;
    const int w    = threadIdx.x >> 6;
    const int h    = lane >> 5;       // half: 0 = even m, 1 = odd m
    const int s    = lane & 31;       // 16B d-block within row
    const uint4* msrow = (const uint4*)msd;   // row stride = 32 uint4 (512 B)
    const int h3 = 3 * h;

    for (int r = 0; r < 4; ++r) {
        const int pi = w * 4 + r;
        const uint4* bp = (const uint4*)&bestS[pi][0];
        float a[8] = {0.f,0.f,0.f,0.f,0.f,0.f,0.f,0.f};

#pragma unroll
        for (int g = 0; g < 4; ++g) {      // 16 m per group
            uint4 bb = bp[g];              // LDS broadcast (same addr all lanes)
            uint32_t W[4] = {bb.x, bb.y, bb.z, bb.w};
            if (h) {                       // pre-shift so target byte is at 0/16
#pragma unroll
                for (int q = 0; q < 4; ++q) W[q] >>= 8;
            }
#pragma unroll
            for (int j = 0; j < 8; ++j) {  // m = 16g + 2j + h
                const uint32_t n = (W[j >> 1] >> (16 * (j & 1))) & 3u;
                const int rowidx = 48 * g + 6 * j + h3 + (int)n;   // 3m + n
                const uint4 q4 = msrow[rowidx * 32 + s];
                a[0] += __uint_as_float(q4.x << 16);
                a[1] += __uint_as_float(q4.x & 0xffff0000u);
                a[2] += __uint_as_float(q4.y << 16);
                a[3] += __uint_as_float(q4.y & 0xffff0000u);
                a[4] += __uint_as_float(q4.z << 16);
                a[5] += __uint_as_float(q4.z & 0xffff0000u);
                a[6] += __uint_as_float(q4.w << 16);
                a[7] += __uint_as_float(q4.w & 0xffff0000u);
            }
        }

        // cross-half reduce (even-m half + odd-m half)
#pragma unroll
        for (int k = 0; k < 8; ++k) a[k] += __shfl_xor(a[k], 32, 64);

        if (h == 0) {
            float* op = out + (size_t)(p0 + pi) * DD + s * 8;
            ((float4*)op)[0] = make_float4(a[0], a[1], a[2], a[3]);
            ((float4*)op)[1] = make_float4(a[4], a[5], a[6], a[7]);
        }
    }
}

extern "C" void kernel_launch(void* const* d_in, const int* in_sizes, int n_in,
                              void* d_out, int out_size, void* d_ws, size_t ws_size,
                              hipStream_t stream) {
    (void)in_sizes; (void)n_in; (void)out_size; (void)ws_size;
    const float* x    = (const float*)d_in[0];   // (B, L, D)
    const float* mem  = (const float*)d_in[1];   // (SLOTS, NG, D)
    const float* bias = (const float*)d_in[2];   // (SLOTS, NG)
    float* out = (float*)d_out;                  // (B, L, D)
    float* S   = (float*)d_ws;                   // (MN, PT) = 6.29 MB

    score_kernel<<<256, 512, 0, stream>>>(x, mem, bias, S);
    gather_kernel<<<256, 512, 0, stream>>>(S, mem, bias, out);
}

// Round 4
// 80.737 us; speedup vs baseline: 1.9136x; 1.5425x over previous
//
#include <hip/hip_runtime.h>
#include <stdint.h>

#define LL   2048
#define DD   256
#define SLOTS 64
#define MN   192
#define PT   8192          // B*L

typedef _Float16 half8 __attribute__((ext_vector_type(8)));
typedef float    f32x4 __attribute__((ext_vector_type(4)));

// ws layout (f16 elements): four 49152-element arrays = 384 KB total
//  aS_h/aS_l: mem as A-operand frags for score GEMM  (M=mn, K=d)
//  bG_h/bG_l: mem as B-operand frags for select GEMM (K=mn, N=d)
#define FRAG_ELEMS (MN * DD)   // 49152

// ---------------- K0: fragment prep ----------------
// A-frag (16x16x32): lane holds A[m=lane&15][k=quad*8+j]
// B-frag:            lane holds B[k=quad*8+j][n=lane&15]
__global__ __launch_bounds__(256) void prep_kernel(
    const float* __restrict__ mem,
    _Float16* __restrict__ aS_h, _Float16* __restrict__ aS_l,
    _Float16* __restrict__ bG_h, _Float16* __restrict__ bG_l)
{
    const int e = blockIdx.x * 256 + threadIdx.x;   // grid 192 -> 49152
    const int mn = e >> 8;
    const int d  = e & 255;
    const float v = mem[e];
    const _Float16 h  = (_Float16)v;
    const _Float16 lo = (_Float16)(v - (float)h);

    // score GEMM: A = mem[mn][d], tiles of 16 mn, K-chunks of 32 d
    {
        const int tm = mn >> 4, r = mn & 15;
        const int c = d >> 5, q = (d >> 3) & 3, j = d & 7;
        const int i1 = ((tm * 8 + c) * 64 + (q * 16 + r)) * 8 + j;
        aS_h[i1] = h; aS_l[i1] = lo;
    }
    // select GEMM: B = mem[mn][d], K-chunks of 32 mn, n-tiles of 16 d
    {
        const int c2 = mn >> 5, q2 = (mn >> 3) & 3, j2 = mn & 7;
        const int td = d >> 4, n2 = d & 15;
        const int i2 = ((td * 6 + c2) * 64 + (q2 * 16 + n2)) * 8 + j2;
        bG_h[i2] = h; bG_l[i2] = lo;
    }
}

// ---------------- K1: fused score-MFMA + argmax + select-MFMA ----------------
// grid 512, block 256 (4 waves). Block -> 16 output p rows; score window 32 rows
// (2 p-tiles) starting at p0-2.
__global__ __launch_bounds__(256) void fused_kernel(
    const float* __restrict__ x, const float* __restrict__ bias,
    const _Float16* __restrict__ aS_h, const _Float16* __restrict__ aS_l,
    const _Float16* __restrict__ bG_h, const _Float16* __restrict__ bG_l,
    float* __restrict__ out)
{
    __shared__ _Float16 xfh[2 * 8 * 64 * 8];   // 16 KB: x window as B-frags (hi)
    __shared__ _Float16 xfl[2 * 8 * 64 * 8];   // 16 KB (lo)
    __shared__ float    scores[MN * 33];       // sims, stride 33 (25.3 KB)
    __shared__ float    biasS[MN];
    __shared__ unsigned int selS[16 * 8];      // 192-bit selection mask per pl

    const int p0   = blockIdx.x * 16;
    const int tid  = threadIdx.x;
    const int lane = tid & 63;
    const int w    = tid >> 6;        // wave 0..3

    // ---- Phase A: stage x window -> f16 hi/lo B-fragments in LDS ----
    if (tid < 128) selS[tid] = 0u;
    if (tid < MN)  biasS[tid] = bias[tid];
    {
        const int c  = tid & 7;        // k-chunk
        const int rr = tid >> 3;       // window row 0..31
        int g = p0 - 2 + rr;
        g = g < 0 ? 0 : (g > PT - 1 ? PT - 1 : g);
        const float4* xr = (const float4*)(x + (size_t)g * DD + c * 32);
        const int pt = rr >> 4, lr = rr & 15;
#pragma unroll
        for (int q = 0; q < 4; ++q) {
            const float4 u = xr[q * 2];
            const float4 v = xr[q * 2 + 1];
            float f[8] = {u.x, u.y, u.z, u.w, v.x, v.y, v.z, v.w};
            half8 hi, lo;
#pragma unroll
            for (int j = 0; j < 8; ++j) {
                const _Float16 h = (_Float16)f[j];
                hi[j] = h;
                lo[j] = (_Float16)(f[j] - (float)h);
            }
            const int base = ((pt * 8 + c) * 64 + q * 16 + lr) * 8;
            *(half8*)(xfh + base) = hi;
            *(half8*)(xfl + base) = lo;
        }
    }
    __syncthreads();

    // ---- Phase B: score GEMM. sims[mn][wp] = dot(mem[mn,:], x[win wp,:]) ----
    // wave w: mn-tiles {3w, 3w+1, 3w+2} x 2 p-tiles
    {
        f32x4 acc[3][2];
#pragma unroll
        for (int i = 0; i < 3; ++i)
#pragma unroll
            for (int p = 0; p < 2; ++p) acc[i][p] = (f32x4){0.f, 0.f, 0.f, 0.f};

#pragma unroll 2
        for (int c = 0; c < 8; ++c) {
            half8 ah[3], al[3], bh[2], bl[2];
#pragma unroll
            for (int i = 0; i < 3; ++i) {
                const int tm = w * 3 + i;
                const size_t off = (size_t)((tm * 8 + c) * 64 + lane) * 8;
                ah[i] = *(const half8*)(aS_h + off);
                al[i] = *(const half8*)(aS_l + off);
            }
#pragma unroll
            for (int p = 0; p < 2; ++p) {
                const int base = ((p * 8 + c) * 64 + lane) * 8;
                bh[p] = *(const half8*)(xfh + base);
                bl[p] = *(const half8*)(xfl + base);
            }
#pragma unroll
            for (int i = 0; i < 3; ++i)
#pragma unroll
                for (int p = 0; p < 2; ++p) {
                    acc[i][p] = __builtin_amdgcn_mfma_f32_16x16x32_f16(ah[i], bh[p], acc[i][p], 0, 0, 0);
                    acc[i][p] = __builtin_amdgcn_mfma_f32_16x16x32_f16(ah[i], bl[p], acc[i][p], 0, 0, 0);
                    acc[i][p] = __builtin_amdgcn_mfma_f32_16x16x32_f16(al[i], bh[p], acc[i][p], 0, 0, 0);
                }
        }

        // C layout: col=lane&15 (=wp within ptile), row=quad*4+reg (=mn within tile)
        const int q = lane >> 4, col = lane & 15;
#pragma unroll
        for (int i = 0; i < 3; ++i) {
            const int tm = w * 3 + i;
#pragma unroll
            for (int p = 0; p < 2; ++p) {
                const int wp = p * 16 + col;
#pragma unroll
                for (int r = 0; r < 4; ++r) {
                    const int mn = tm * 16 + q * 4 + r;
                    scores[mn * 33 + wp] = acc[i][p][r];
                }
            }
        }
    }
    __syncthreads();

    // ---- Phase C: argmax over n (first-max tiebreak) -> selection bitmask ----
#pragma unroll
    for (int it = 0; it < 4; ++it) {
        const int t2 = tid + it * 256;
        const int pl = t2 & 15;
        const int m  = t2 >> 4;           // 0..63
        const int p  = p0 + pl;
        const int l  = p & (LL - 1);
        const float v0 = ((l >= 2) ? scores[(3 * m + 0) * 33 + pl + 0] : 0.f) + biasS[3 * m + 0];
        const float v1 = ((l >= 1) ? scores[(3 * m + 1) * 33 + pl + 1] : 0.f) + biasS[3 * m + 1];
        const float v2 =              scores[(3 * m + 2) * 33 + pl + 2]       + biasS[3 * m + 2];
        int bn = 0; float bv = v0;
        if (v1 > bv) { bv = v1; bn = 1; }
        if (v2 > bv) { bv = v2; bn = 2; }
        const int mnb = 3 * m + bn;
        atomicOr(&selS[pl * 8 + (mnb >> 5)], 1u << (mnb & 31));
    }
    __syncthreads();

    // ---- Phase D: select GEMM. out[p][d] = SEL[p][mn] * mem[mn][d] ----
    // wave w: d-tiles w*4 .. w*4+3. SEL is A-operand (exact 0/1 f16).
    {
        const int q  = lane >> 4, col = lane & 15;
        const int qb = q * 8;
        unsigned int sw[6];
#pragma unroll
        for (int c = 0; c < 6; ++c) sw[c] = selS[col * 8 + c];   // pl = col = lane&15

        f32x4 acc2[4];
#pragma unroll
        for (int i = 0; i < 4; ++i) acc2[i] = (f32x4){0.f, 0.f, 0.f, 0.f};

        const _Float16 ONE = (_Float16)1.f, ZERO = (_Float16)0.f;
#pragma unroll
        for (int c = 0; c < 6; ++c) {
            half8 sel;
#pragma unroll
            for (int j = 0; j < 8; ++j)
                sel[j] = ((sw[c] >> (qb + j)) & 1u) ? ONE : ZERO;
#pragma unroll
            for (int i = 0; i < 4; ++i) {
                const int td = w * 4 + i;
                const size_t off = (size_t)((td * 6 + c) * 64 + lane) * 8;
                const half8 mh = *(const half8*)(bG_h + off);
                const half8 ml = *(const half8*)(bG_l + off);
                acc2[i] = __builtin_amdgcn_mfma_f32_16x16x32_f16(sel, mh, acc2[i], 0, 0, 0);
                acc2[i] = __builtin_amdgcn_mfma_f32_16x16x32_f16(sel, ml, acc2[i], 0, 0, 0);
            }
        }

        // C layout: row=quad*4+reg = pl, col = d within tile
#pragma unroll
        for (int i = 0; i < 4; ++i) {
            const int td = w * 4 + i;
#pragma unroll
            for (int r = 0; r < 4; ++r) {
                out[(size_t)(p0 + q * 4 + r) * DD + td * 16 + col] = acc2[i][r];
            }
        }
    }
}

extern "C" void kernel_launch(void* const* d_in, const int* in_sizes, int n_in,
                              void* d_out, int out_size, void* d_ws, size_t ws_size,
                              hipStream_t stream) {
    (void)in_sizes; (void)n_in; (void)out_size; (void)ws_size;
    const float* x    = (const float*)d_in[0];
    const float* mem  = (const float*)d_in[1];
    const float* bias = (const float*)d_in[2];
    float* out = (float*)d_out;

    _Float16* aS_h = (_Float16*)d_ws;
    _Float16* aS_l = aS_h + FRAG_ELEMS;
    _Float16* bG_h = aS_l + FRAG_ELEMS;
    _Float16* bG_l = bG_h + FRAG_ELEMS;

    prep_kernel<<<FRAG_ELEMS / 256, 256, 0, stream>>>(mem, aS_h, aS_l, bG_h, bG_l);
    fused_kernel<<<PT / 16, 256, 0, stream>>>(x, bias, aS_h, aS_l, bG_h, bG_l, out);
}